// Round 11
// baseline (1221.145 us; speedup 1.0000x reference)
//
#include <hip/hip_runtime.h>
#include <cstddef>

#define BB   8
#define VV   25
#define TT   128
#define CC   256
#define NHH  8
#define DKK  32
#define DFFF 1024
#define ITER 4
#define NN   (BB*VV)     // 200
#define NT   (NN*TT)     // 25600
#define LL1  (TT+1)      // 129
#define EPS_LN 1e-6f
#define EPS_BN 1e-5f
#define SLOPE  0.01f
#define SCALE_F 0.17677669529663687f   // 1/sqrt(32)

typedef unsigned short ushort_t;
typedef __attribute__((ext_vector_type(8))) short short8;
typedef __attribute__((ext_vector_type(4))) short short4_t;
typedef __attribute__((ext_vector_type(4))) float floatx4;

union U8 { short8 v; ushort_t u[8]; };

__device__ __forceinline__ float bf2f(ushort_t u) {
    union { unsigned int i; float f; } x; x.i = ((unsigned int)u) << 16; return x.f;
}
__device__ __forceinline__ ushort_t f2bf(float f) {
    union { float f; unsigned int i; } x; x.f = f;
    unsigned int r = x.i + 0x7FFFu + ((x.i >> 16) & 1u);   // RNE
    return (ushort_t)(r >> 16);
}
// finalize raw BN sums -> (mean, rstd)
__device__ __forceinline__ float2 bn_fin(float s, float ss) {
    float m = s * (1.0f/NT);
    float var = ss * (1.0f/NT) - m*m; if (var < 0.f) var = 0.f;
    return make_float2(m, rsqrtf(var + EPS_BN));
}

// async global->LDS, 16B per lane (dest must be wave-uniform base; HW adds lane*16)
__device__ __forceinline__ void gl_lds16(const ushort_t* g, ushort_t* l) {
    __builtin_amdgcn_global_load_lds(
        (const __attribute__((address_space(1))) unsigned int*)g,
        (__attribute__((address_space(3))) unsigned int*)l,
        16, 0, 0);
}

// load 32 bf16 (contiguous) -> f32 regs
__device__ __forceinline__ void ld32(const ushort_t* p, float* q) {
    #pragma unroll
    for (int c8 = 0; c8 < 4; c8++) {
        U8 u; u.v = *(const short8*)(p + c8*8);
        #pragma unroll
        for (int j = 0; j < 8; j++) q[c8*8+j] = bf2f(u.u[j]);
    }
}
__device__ __forceinline__ float dot32(const ushort_t* p, const float* q) {
    float s = 0.f;
    #pragma unroll
    for (int c8 = 0; c8 < 4; c8++) {
        U8 u; u.v = *(const short8*)(p + c8*8);
        #pragma unroll
        for (int j = 0; j < 8; j++) s += q[c8*8+j]*bf2f(u.u[j]);
    }
    return s;
}
__device__ __forceinline__ void acc32(const ushort_t* p, float e, float* av) {
    #pragma unroll
    for (int c8 = 0; c8 < 4; c8++) {
        U8 u; u.v = *(const short8*)(p + c8*8);
        #pragma unroll
        for (int j = 0; j < 8; j++) av[c8*8+j] += e*bf2f(u.u[j]);
    }
}

// ---------------------------------------------------------------------------
__global__ __launch_bounds__(256) void k_zero(float* __restrict__ p, int n)
{
    int i = blockIdx.x*256 + threadIdx.x;
    if (i < n) p[i] = 0.f;
}
// strided cast/copy: dst[(i/per)*dstride + i%per] = src[i]
__global__ __launch_bounds__(256) void k_cast2(const float* __restrict__ src,
    ushort_t* __restrict__ dst, int per, int dstride, int total)
{
    int i = blockIdx.x*256 + threadIdx.x;
    if (i < total) dst[(size_t)(i/per)*dstride + (i%per)] = f2bf(src[i]);
}
__global__ __launch_bounds__(256) void k_copy2(const float* __restrict__ src,
    float* __restrict__ dst, int per, int dstride, int total)
{
    int i = blockIdx.x*256 + threadIdx.x;
    if (i < total) dst[(size_t)(i/per)*dstride + (i%per)] = src[i];
}

// ---------------------------------------------------------------------------
// embed: nodesf[nt][c] f32 TM + embs_bf TM + relay[n][c]=mean_t. LDS transpose.
__global__ __launch_bounds__(128) void k_embed(const float* __restrict__ data,
    float* __restrict__ nodesf, ushort_t* __restrict__ embs_bf, float* __restrict__ relay)
{
    __shared__ float tile[32][TT+1];
    int cc0 = blockIdx.x*32, n = blockIdx.y;
    int b = n / VV, v = n % VV, t = threadIdx.x;
    for (int cl = 0; cl < 32; cl++)
        tile[cl][t] = data[(((size_t)b*CC + cc0 + cl)*VV + v)*TT + t];
    __syncthreads();
    if (t < 32) {
        float s = 0.f;
        for (int tt = 0; tt < TT; tt++) s += tile[t][tt];
        relay[n*CC + cc0 + t] = s * (1.0f/TT);
    }
    #pragma unroll 8
    for (int it = 0; it < 32; it++) {
        int t_l = it*4 + (t >> 5), c_l = t & 31;
        float val = tile[c_l][t_l];
        size_t o = (size_t)(n*TT + t_l)*CC + cc0 + c_l;
        nodesf[o] = val;
        embs_bf[o] = f2bf(val);
    }
}

// ---------------------------------------------------------------------------
// LayerNorm TM in-place + bf16 TM copy. One wave per token. (layer 0 only)
__global__ __launch_bounds__(256) void k_layernorm(float* __restrict__ x,
    ushort_t* __restrict__ outb, const float* __restrict__ g, const float* __restrict__ b)
{
    int wave = threadIdx.x >> 6, lane = threadIdx.x & 63;
    size_t base = (size_t)(blockIdx.x*4 + wave)*CC + lane*4;
    float4 v = *(float4*)&x[base];
    float s  = v.x + v.y + v.z + v.w;
    float ss = v.x*v.x + v.y*v.y + v.z*v.z + v.w*v.w;
    #pragma unroll
    for (int o = 32; o; o >>= 1) { s += __shfl_xor(s, o); ss += __shfl_xor(ss, o); }
    float m = s * (1.0f/CC);
    float var = ss * (1.0f/CC) - m*m; if (var < 0.f) var = 0.f;
    float rs = rsqrtf(var + EPS_LN);
    float4 gg = *(const float4*)&g[lane*4];
    float4 bb = *(const float4*)&b[lane*4];
    v.x = (v.x - m)*rs*gg.x + bb.x;
    v.y = (v.y - m)*rs*gg.y + bb.y;
    v.z = (v.z - m)*rs*gg.z + bb.z;
    v.w = (v.w - m)*rs*gg.w + bb.w;
    *(float4*)&x[base] = v;
    ushort_t o4[4] = {f2bf(v.x), f2bf(v.y), f2bf(v.z), f2bf(v.w)};
    *(short4_t*)&outb[base] = *(short4_t*)o4;
}

// ---------------------------------------------------------------------------
// bf16 MFMA GEMM. R16: 256x128 M-DOUBLED tile — amortizes the fixed
// ~2000cy/phase sync stall over 2x output per block (block-phases for the
// merged dispatch: 16000 -> 8320). 8 waves, each owns 64x64 (acc 4x4).
// Triple-buffered 72KB (2 blocks/CU, 16 waves/CU), counted vmcnt(3) depth-2
// pipeline — the exact R8 PHASE structure with batch=3 loads/wave. Same
// per-matrix chunk swizzle as R8 (measured 0 bank conflicts); B region at
// ushort offset 8192. XCD map: mt = xcd*13 + idx/ntiles, early-return for
// mt >= 100. R8 swapped-operand MFMA + vectorized epilogue; R10 DUAL-JOB +
// STATS; R11 FL_HM head-major output.
#define FL_RELU  1
#define FL_BF16  2
#define FL_RESBN 4
#define FL_HM    8

#define STAGE(SBUF, T_) do {                                                \
    gl_lds16(gSrc[0] + (T_)*32, &SBUF[dstOff[0]]);                          \
    gl_lds16(gSrc[1] + (T_)*32, &SBUF[dstOff[1]]);                          \
    gl_lds16(gSrc[2] + (T_)*32, &SBUF[dstOff[2]]);                          \
    } while (0)

// swapped operand order: mfma(B_frag, A_frag, acc) -> transposed fragment:
// lane holds m = ...+fc (fixed), n = ...+fr*4+r (4 consecutive).
#define COMPUTE(SBUF) do {                                                  \
    short8 af_[4], bf_[4];                                                  \
    _Pragma("unroll")                                                       \
    for (int mi_ = 0; mi_ < 4; mi_++)                                       \
        af_[mi_] = *(const short8*)&SBUF[aOff[mi_]];                        \
    _Pragma("unroll")                                                       \
    for (int ni_ = 0; ni_ < 4; ni_++)                                       \
        bf_[ni_] = *(const short8*)&SBUF[bOff[ni_]];                        \
    _Pragma("unroll")                                                       \
    for (int mi_ = 0; mi_ < 4; mi_++)                                       \
        _Pragma("unroll")                                                   \
        for (int ni_ = 0; ni_ < 4; ni_++)                                   \
            acc[mi_][ni_] = __builtin_amdgcn_mfma_f32_16x16x32_bf16(        \
                bf_[ni_], af_[mi_], acc[mi_][ni_], 0, 0, 0);                \
    } while (0)

#define WAITVL(S_) asm volatile("s_waitcnt vmcnt(" S_ ") lgkmcnt(0)" ::: "memory")

// phase t: prefetch tile t+2; compute tile t; counted wait for tile t+1
// (this wave's t+2 batch of 3 stays in flight); barrier.
#define PHASE(CBUF, PBUF, T_) do {                                          \
    if ((T_) + 2 < NK) STAGE(PBUF, (T_) + 2);                               \
    COMPUTE(CBUF);                                                          \
    if ((T_) + 1 < NK) {                                                    \
        __builtin_amdgcn_sched_barrier(0);                                  \
        if ((T_) + 2 < NK) WAITVL("3");                                     \
        else               WAITVL("0");                                     \
        __builtin_amdgcn_s_barrier();                                       \
        __builtin_amdgcn_sched_barrier(0);                                  \
    }                                                                       \
    } while (0)

template<int K, int STATS>
__global__ __launch_bounds__(512, STATS ? 2 : 4) void k_gemm_mfma(
    const ushort_t* A, const ushort_t* B, const float* bias,
    const float* rx, const float* __restrict__ rawms,
    const float* __restrict__ bng, const float* __restrict__ bnb,
    float* outf, ushort_t* outb, int ostride, int ntiles_n, int flags,
    const ushort_t* A2, const ushort_t* B2, const float* bias2,
    ushort_t* outb2, int ostride2, int ntiles_n2,
    float* stats_acc)
{
    // buffer = 24KB: A tile 256x32 at ushort [0,8192), B tile 128x32 at
    // [8192,12288)
    __shared__ ushort_t sT0[12288];
    __shared__ ushort_t sT1[12288];
    __shared__ ushort_t sT2[12288];
    const int pid = blockIdx.x;
    const int xcd = pid & 7, idx = pid >> 3;
    const int ntile_tot = ntiles_n + ntiles_n2;
    const int nt_i = idx % ntile_tot;
    const int mt   = xcd*13 + idx/ntile_tot;     // 100 m-tiles of 256 rows
    if (mt >= 100) return;
    const int m0 = mt * 256;
    // job select (block-uniform)
    const ushort_t* Ap;  const ushort_t* Bp;  const float* biasp;
    ushort_t* outbp;  int ostridep, n0;
    if (nt_i < ntiles_n) {
        Ap = A;  Bp = B;  biasp = bias;  outbp = outb;
        ostridep = ostride;  n0 = nt_i*128;
    } else {
        Ap = A2; Bp = B2; biasp = bias2; outbp = outb2;
        ostridep = ostride2; n0 = (nt_i - ntiles_n)*128;
    }
    const int tid = threadIdx.x;
    const int lane = tid & 63, wave = tid >> 6;      // 0..7
    const int wm = (wave >> 1) * 64, wn = (wave & 1) * 64;
    const int fr = lane >> 4, fc = lane & 15;

    // staging: 24 x 1KB slots per phase (A: slots 0-15, B: 16-23);
    // wave w owns slots {3w, 3w+1, 3w+2}. chunk (row,kc) at slot
    // row*4 + ((kc + (row>>1)) & 3); inverse gives global src per lane.
    const ushort_t* gSrc[3];
    int dstOff[3];
    #pragma unroll
    for (int j = 0; j < 3; j++) {
        int s  = wave*3 + j;
        bool isA = (s < 16);
        int sl = isA ? s : s - 16;
        int g  = sl*64 + lane;
        int row = g >> 2;
        int kcs = ((g & 3) - (row >> 1)) & 3;
        gSrc[j] = (isA ? Ap + (size_t)(m0 + row)*K
                       : Bp + (size_t)(n0 + row)*K) + kcs*8;
        dstOff[j] = (isA ? 0 : 8192) + sl*512;     // wave-uniform (16B slots)
    }
    // ds_read fragment offsets (ushorts), loop-invariant
    int aOff[4], bOff[4];
    #pragma unroll
    for (int mi = 0; mi < 4; mi++) {
        int row = wm + mi*16 + fc;                  // 0..255
        aOff[mi] = row*32 + (((fr + (row >> 1)) & 3) * 8);
    }
    #pragma unroll
    for (int ni = 0; ni < 4; ni++) {
        int row = wn + ni*16 + fc;                  // 0..127
        bOff[ni] = 8192 + row*32 + (((fr + (row >> 1)) & 3) * 8);
    }

    floatx4 acc[4][4];
    #pragma unroll
    for (int i = 0; i < 4; i++)
        #pragma unroll
        for (int j = 0; j < 4; j++) acc[i][j] = (floatx4){0.f,0.f,0.f,0.f};

    constexpr int NK = K >> 5;
    // prologue: tiles 0,1 in flight; wait for tile 0 (this wave: vmcnt(3))
    STAGE(sT0, 0);
    if (NK > 1) STAGE(sT1, 1);
    __builtin_amdgcn_sched_barrier(0);
    if (NK > 1) WAITVL("3");
    else        WAITVL("0");
    __builtin_amdgcn_s_barrier();
    __builtin_amdgcn_sched_barrier(0);

    #pragma unroll
    for (int tb = 0; tb < NK; tb += 3) {
        PHASE(sT0, sT2, tb);
        if (tb + 1 < NK) PHASE(sT1, sT0, tb + 1);
        if (tb + 2 < NK) PHASE(sT2, sT1, tb + 2);
    }

    // Epilogue: lane (fr,fc) of acc[mi][ni] holds
    // m = m0+wm+mi*16+fc, n = n0+wn+ni*16+fr*4 + r, r=0..3 consecutive.
    float st[4][4], sst[4][4];
    if constexpr (STATS) {
        #pragma unroll
        for (int a = 0; a < 4; a++)
            #pragma unroll
            for (int b2_ = 0; b2_ < 4; b2_++) { st[a][b2_] = 0.f; sst[a][b2_] = 0.f; }
    }
    #pragma unroll
    for (int ni = 0; ni < 4; ni++) {
        int nb = n0 + wn + ni*16 + fr*4;
        float4 bias4 = *(const float4*)&biasp[nb];
        float bm[4] = {0,0,0,0}, bs[4] = {0,0,0,0}, bb2[4] = {0,0,0,0};
        if (flags & FL_RESBN) {
            float4 s1 = *(const float4*)&rawms[nb];
            float4 s2 = *(const float4*)&rawms[CC + nb];
            float4 g4 = *(const float4*)&bng[nb];
            float4 b4 = *(const float4*)&bnb[nb];
            float2 f0 = bn_fin(s1.x, s2.x); float2 f1 = bn_fin(s1.y, s2.y);
            float2 f2 = bn_fin(s1.z, s2.z); float2 f3 = bn_fin(s1.w, s2.w);
            bm[0]=f0.x; bm[1]=f1.x; bm[2]=f2.x; bm[3]=f3.x;
            bs[0]=f0.y*g4.x; bs[1]=f1.y*g4.y; bs[2]=f2.y*g4.z; bs[3]=f3.y*g4.w;
            bb2[0]=b4.x; bb2[1]=b4.y; bb2[2]=b4.z; bb2[3]=b4.w;
        }
        float bia[4] = {bias4.x, bias4.y, bias4.z, bias4.w};
        // head-major base: ((nb>>5)*NT + m)*32 + (nb&31)
        size_t hm_base = ((size_t)(nb >> 5) * NT) * 32 + (nb & 31);
        #pragma unroll
        for (int mi = 0; mi < 4; mi++) {
            int m = m0 + wm + mi*16 + fc;
            size_t idx2 = (flags & FL_HM) ? hm_base + (size_t)m*32
                                          : (size_t)m*ostridep + nb;
            float vals[4];
            #pragma unroll
            for (int r = 0; r < 4; r++) vals[r] = acc[mi][ni][r] + bia[r];
            if (flags & FL_RESBN) {
                float4 rx4 = *(const float4*)&rx[idx2];
                float rxa[4] = {rx4.x, rx4.y, rx4.z, rx4.w};
                #pragma unroll
                for (int r = 0; r < 4; r++)
                    vals[r] += (rxa[r] - bm[r])*bs[r] + bb2[r];
            }
            if (flags & FL_RELU)
                #pragma unroll
                for (int r = 0; r < 4; r++) vals[r] = fmaxf(vals[r], 0.f);
            if constexpr (STATS) {
                #pragma unroll
                for (int r = 0; r < 4; r++) {
                    st[ni][r] += vals[r];
                    sst[ni][r] += vals[r]*vals[r];
                }
            }
            if (flags & FL_BF16) {
                ushort_t o4[4] = {f2bf(vals[0]), f2bf(vals[1]),
                                  f2bf(vals[2]), f2bf(vals[3])};
                *(short4_t*)&outbp[idx2] = *(short4_t*)o4;
            } else {
                float4 ov = make_float4(vals[0], vals[1], vals[2], vals[3]);
                *(float4*)&outf[idx2] = ov;
            }
        }
    }
    if constexpr (STATS) {
        // reduce over the 16 fc lanes (same channel set), then atomicAdd
        #pragma unroll
        for (int ni = 0; ni < 4; ni++)
            #pragma unroll
            for (int r = 0; r < 4; r++) {
                float s_ = st[ni][r], ss_ = sst[ni][r];
                #pragma unroll
                for (int msk = 1; msk < 16; msk <<= 1) {
                    s_  += __shfl_xor(s_,  msk);
                    ss_ += __shfl_xor(ss_, msk);
                }
                st[ni][r] = s_; sst[ni][r] = ss_;
            }
        if (fc == 0) {
            #pragma unroll
            for (int ni = 0; ni < 4; ni++)
                #pragma unroll
                for (int r = 0; r < 4; r++) {
                    int ch = n0 + wn + ni*16 + fr*4 + r;
                    atomicAdd(&stats_acc[ch],      st[ni][r]);
                    atomicAdd(&stats_acc[CC + ch], sst[ni][r]);
                }
        }
    }
}

// ---------------------------------------------------------------------------
// Small fp32 GEMM (relay path). R9 core: one barrier pair per 256-wide
// K-chunk, float4 staging + ds_read_b128 dot product.
__global__ __launch_bounds__(256) void k_sgemm(
    const float* __restrict__ W, const float* __restrict__ X,
    const float* __restrict__ bias, const float* __restrict__ res,
    float* __restrict__ out, int K, int OUT, int do_relu)
{
    __shared__ float sW[16][260];
    __shared__ float sX[16][260];
    int o0 = blockIdx.x*16, n0 = blockIdx.y*16;
    int tx = threadIdx.x, ty = threadIdx.y;
    int tid = ty*16 + tx;
    float acc0 = 0.f, acc1 = 0.f;
    for (int kc = 0; kc < K; kc += 256) {
        #pragma unroll
        for (int j = 0; j < 4; j++) {
            int lin = tid + j*256;
            int row = lin >> 6, c4 = (lin & 63)*4;
            *(float4*)&sW[row][c4] = *(const float4*)&W[(size_t)(o0+row)*K + kc + c4];
            float4 xv = make_float4(0.f,0.f,0.f,0.f);
            if (n0 + row < NN) xv = *(const float4*)&X[(size_t)(n0+row)*K + kc + c4];
            *(float4*)&sX[row][c4] = xv;
        }
        __syncthreads();
        #pragma unroll 8
        for (int k4 = 0; k4 < 64; k4 += 2) {
            float4 w0 = *(const float4*)&sW[tx][k4*4];
            float4 x0 = *(const float4*)&sX[ty][k4*4];
            float4 w1 = *(const float4*)&sW[tx][k4*4+4];
            float4 x1 = *(const float4*)&sX[ty][k4*4+4];
            acc0 += w0.x*x0.x + w0.y*x0.y + w0.z*x0.z + w0.w*x0.w;
            acc1 += w1.x*x1.x + w1.y*x1.y + w1.z*x1.z + w1.w*x1.w;
        }
        __syncthreads();
    }
    float accv = acc0 + acc1;
    int o = o0 + tx, n = n0 + ty;
    if (n < NN) {
        float val = accv + bias[o];
        if (res) val += res[(size_t)n*OUT + o];
        if (do_relu) val = fmaxf(val, 0.f);
        out[(size_t)n*OUT + o] = val;
    }
}

// ---------------------------------------------------------------------------
// tj attention, HEAD-MAJOR inputs (R11): qkv [24 heads][NT][32] bf16
// (q:0-7, k:8-15, v:16-23), ekv [16][NT][32] bf16 (ek:0-7, ev:8-15).
// rel [n][1280] f32, xln [nt][256] f32. Zero LDS — occupancy carries it.
__global__ __launch_bounds__(128) void k_attn_tj(
    const ushort_t* __restrict__ qkv, const ushort_t* __restrict__ ekv,
    const float* __restrict__ rel, const float* __restrict__ xln,
    float* __restrict__ out)
{
    int t = threadIdx.x, h = blockIdx.x, n = blockIdx.y;
    int nt = n*TT + t;
    const ushort_t* qp = qkv + ((size_t)h*NT       + nt)*32;
    const ushort_t* kp = qkv + ((size_t)(8+h)*NT   + nt)*32;
    const ushort_t* vp = qkv + ((size_t)(16+h)*NT  + nt)*32;
    const ushort_t* ep = ekv + ((size_t)h*NT       + nt)*32;
    const ushort_t* evp= ekv + ((size_t)(8+h)*NT   + nt)*32;
    const float*    rp = rel + n*1280 + h*32;   // k at +0, v at +256

    float qv[32];
    ld32(qp, qv);
    float s0 = 0.f, s1, s2 = 0.f, s3, s4 = 0.f;
    s1 = dot32(kp, qv);
    s3 = dot32(ep, qv);
    #pragma unroll
    for (int j = 0; j < 8; j++) {
        float4 rv4 = *(const float4*)&rp[j*4];
        s4 += qv[j*4]*rv4.x + qv[j*4+1]*rv4.y + qv[j*4+2]*rv4.z + qv[j*4+3]*rv4.w;
    }
    if (t > 0)    s0 = dot32(kp - 32, qv);
    if (t < TT-1) s2 = dot32(kp + 32, qv);

    s0 *= SCALE_F; s1 *= SCALE_F; s2 *= SCALE_F; s3 *= SCALE_F; s4 *= SCALE_F;
    float mx = fmaxf(fmaxf(fmaxf(s0, s1), fmaxf(s2, s3)), s4);
    float e0 = expf(s0-mx), e1 = expf(s1-mx), e2 = expf(s2-mx), e3 = expf(s3-mx), e4 = expf(s4-mx);
    float inv = 1.f/(e0+e1+e2+e3+e4);
    e0 *= inv; e1 *= inv; e2 *= inv; e3 *= inv; e4 *= inv;

    float av[32];
    #pragma unroll
    for (int d = 0; d < 32; d++) av[d] = 0.f;
    acc32(vp, e1, av);
    acc32(evp, e3, av);
    if (t > 0)    acc32(vp - 32, e0, av);
    if (t < TT-1) acc32(vp + 32, e2, av);
    #pragma unroll
    for (int j = 0; j < 8; j++) {
        float4 rv4 = *(const float4*)&rp[256 + j*4];
        av[j*4] += e4*rv4.x; av[j*4+1] += e4*rv4.y; av[j*4+2] += e4*rv4.z; av[j*4+3] += e4*rv4.w;
    }
    const float* xp = xln + (size_t)nt*CC + h*32;
    float* op = out + (size_t)nt*CC + h*32;
    #pragma unroll
    for (int j = 0; j < 8; j++) {
        float4 xv = *(const float4*)&xp[j*4];
        float4 ov;
        ov.x = xv.x + av[j*4]; ov.y = xv.y + av[j*4+1];
        ov.z = xv.z + av[j*4+2]; ov.w = xv.w + av[j*4+3];
        *(float4*)&op[j*4] = ov;
    }
}

// ---------------------------------------------------------------------------
// BN stats over tokens, TM input; atomicAdd raw sums into accum[512]
// (accum must be zeroed earlier in this launch).
__global__ __launch_bounds__(256) void k_bnstats_tm(const float* __restrict__ x,
    float* __restrict__ accum)
{
    __shared__ float lds[8][256];
    int w = threadIdx.x >> 6, lane = threadIdx.x & 63;
    size_t base = (size_t)blockIdx.x*TT*CC;
    float s[4] = {0,0,0,0}, ss[4] = {0,0,0,0};
    for (int tok = w; tok < TT; tok += 4) {
        float4 v = *(const float4*)&x[base + (size_t)tok*CC + lane*4];
        s[0] += v.x; s[1] += v.y; s[2] += v.z; s[3] += v.w;
        ss[0] += v.x*v.x; ss[1] += v.y*v.y; ss[2] += v.z*v.z; ss[3] += v.w*v.w;
    }
    #pragma unroll
    for (int j = 0; j < 4; j++) { lds[w][lane*4+j] = s[j]; lds[4+w][lane*4+j] = ss[j]; }
    __syncthreads();
    int c = threadIdx.x;
    float ps  = lds[0][c]+lds[1][c]+lds[2][c]+lds[3][c];
    float pss = lds[4][c]+lds[5][c]+lds[6][c]+lds[7][c];
    atomicAdd(&accum[c], ps);
    atomicAdd(&accum[CC + c], pss);
}

// ---------------------------------------------------------------------------
// BN1 apply (no leaky), raw sums, bf16 TM out only
__global__ __launch_bounds__(256) void k_bn_apply_raw(const float* __restrict__ x,
    const float* __restrict__ acc, const float* __restrict__ g, const float* __restrict__ b,
    ushort_t* __restrict__ outb)
{
    size_t base = ((size_t)blockIdx.x*256 + threadIdx.x)*4;
    int c0 = (int)(base & (CC-1));
    float4 v  = *(const float4*)&x[base];
    float4 a1 = *(const float4*)&acc[c0];
    float4 a2 = *(const float4*)&acc[CC + c0];
    float4 g4 = *(const float4*)&g[c0];
    float4 b4 = *(const float4*)&b[c0];
    float vals[4] = {v.x,v.y,v.z,v.w};
    float s1v[4] = {a1.x,a1.y,a1.z,a1.w};
    float s2v[4] = {a2.x,a2.y,a2.z,a2.w};
    float gg[4] = {g4.x,g4.y,g4.z,g4.w};
    float bb[4] = {b4.x,b4.y,b4.z,b4.w};
    ushort_t o4[4];
    #pragma unroll
    for (int j = 0; j < 4; j++) {
        float2 f = bn_fin(s1v[j], s2v[j]);
        o4[j] = f2bf((vals[j] - f.x)*f.y*gg[j] + bb[j]);
    }
    *(short4_t*)&outb[base] = *(short4_t*)o4;
}

// Fused BN2 + leaky + next-layer LN. One wave/token.
__global__ __launch_bounds__(256) void k_bn_ln(const float* __restrict__ x,
    const float* __restrict__ acc, const float* __restrict__ fg, const float* __restrict__ fb,
    const float* __restrict__ lg, const float* __restrict__ lb,
    float* __restrict__ xlnf, ushort_t* __restrict__ xlnb, ushort_t* __restrict__ nodesb)
{
    int wave = threadIdx.x >> 6, lane = threadIdx.x & 63;
    int c0 = lane*4;
    size_t base = (size_t)(blockIdx.x*4 + wave)*CC + c0;
    float4 v  = *(const float4*)&x[base];
    float4 a1 = *(const float4*)&acc[c0];
    float4 a2 = *(const float4*)&acc[CC + c0];
    float4 g4 = *(const float4*)&fg[c0];
    float4 b4 = *(const float4*)&fb[c0];
    float vals[4] = {v.x,v.y,v.z,v.w};
    float s1v[4] = {a1.x,a1.y,a1.z,a1.w};
    float s2v[4] = {a2.x,a2.y,a2.z,a2.w};
    float gg[4] = {g4.x,g4.y,g4.z,g4.w};
    float bb[4] = {b4.x,b4.y,b4.z,b4.w};
    ushort_t nb4[4];
    #pragma unroll
    for (int j = 0; j < 4; j++) {
        float2 f = bn_fin(s1v[j], s2v[j]);
        float vv = (vals[j] - f.x)*f.y*gg[j] + bb[j];
        vv = vv > 0.f ? vv : SLOPE*vv;
        vals[j] = vv;
        nb4[j] = f2bf(vv);
    }
    *(short4_t*)&nodesb[base] = *(short4_t*)nb4;
    float s  = vals[0]+vals[1]+vals[2]+vals[3];
    float ss = vals[0]*vals[0]+vals[1]*vals[1]+vals[2]*vals[2]+vals[3]*vals[3];
    #pragma unroll
    for (int o = 32; o; o >>= 1) { s += __shfl_xor(s, o); ss += __shfl_xor(ss, o); }
    float m = s * (1.0f/CC);
    float var = ss * (1.0f/CC) - m*m; if (var < 0.f) var = 0.f;
    float rs = rsqrtf(var + EPS_LN);
    float4 lg4 = *(const float4*)&lg[c0];
    float4 lb4 = *(const float4*)&lb[c0];
    float lgv[4] = {lg4.x,lg4.y,lg4.z,lg4.w};
    float lbv[4] = {lb4.x,lb4.y,lb4.z,lb4.w};
    float4 xo;
    ushort_t xb4[4];
    float t0 = (vals[0]-m)*rs*lgv[0] + lbv[0];
    float t1 = (vals[1]-m)*rs*lgv[1] + lbv[1];
    float t2 = (vals[2]-m)*rs*lgv[2] + lbv[2];
    float t3 = (vals[3]-m)*rs*lgv[3] + lbv[3];
    xo.x = t0; xo.y = t1; xo.z = t2; xo.w = t3;
    xb4[0]=f2bf(t0); xb4[1]=f2bf(t1); xb4[2]=f2bf(t2); xb4[3]=f2bf(t3);
    *(float4*)&xlnf[base] = xo;
    *(short4_t*)&xlnb[base] = *(short4_t*)xb4;
}

// final BN + leaky + transpose TM -> d_out [n][c][t], raw sums
__global__ __launch_bounds__(256) void k_bn_out_t(const float* __restrict__ x,
    const float* __restrict__ acc, const float* __restrict__ g, const float* __restrict__ b,
    float* __restrict__ out)
{
    __shared__ float tile[64][65];
    int nt0 = blockIdx.x*64, c0 = blockIdx.y*64;
    int w = threadIdx.x >> 6, lane = threadIdx.x & 63;
    int n = nt0 >> 7, t0 = nt0 & 127;
    int c = c0 + lane;
    float2 f = bn_fin(acc[c], acc[CC + c]);
    float gg = f.y*g[c], mm = f.x, bb = b[c];
    #pragma unroll
    for (int it = 0; it < 16; it++) {
        int tok = it*4 + w;
        float v = x[(size_t)(nt0 + tok)*CC + c];
        v = (v - mm)*gg + bb;
        v = v > 0.f ? v : SLOPE*v;
        tile[tok][lane] = v;
    }
    __syncthreads();
    #pragma unroll
    for (int it = 0; it < 16; it++) {
        int c_l = it*4 + w;
        out[(size_t)(n*CC + c0 + c_l)*TT + t0 + lane] = tile[lane][c_l];
    }
}

// BatchNorm over n only (relay path), x/out [N,C]
__global__ __launch_bounds__(64) void k_bn_relay(const float* __restrict__ x,
    float* __restrict__ out, const float* __restrict__ g, const float* __restrict__ b, int leaky)
{
    int c = blockIdx.x, tid = threadIdx.x;
    float s = 0.f, ss = 0.f;
    for (int n = tid; n < NN; n += 64) { float v = x[(size_t)n*CC + c]; s += v; ss += v*v; }
    for (int off = 32; off; off >>= 1) { s += __shfl_down(s, off); ss += __shfl_down(ss, off); }
    float S = __shfl(s, 0), SS = __shfl(ss, 0);
    float m = S / NN;
    float var = SS / NN - m*m; if (var < 0.f) var = 0.f;
    float rs = rsqrtf(var + EPS_BN);
    float gg = g[c]*rs, bb = b[c];
    for (int n = tid; n < NN; n += 64) {
        float v = (x[(size_t)n*CC + c] - m)*gg + bb;
        if (leaky) v = v > 0.f ? v : SLOPE*v;
        out[(size_t)n*CC + c] = v;
    }
}

// ---------------------------------------------------------------------------
// relay cross-attention; ykv HEAD-MAJOR f32 [16][NT][32] (k:0-7, v:8-15);
// rel [n][1280] (tr_k at +512, tr_v at +768, tr_q at +1024)
__global__ __launch_bounds__(64) void k_attn_tr(
    const float* __restrict__ rel, const float* __restrict__ ykv,
    const float* __restrict__ relay, float* __restrict__ out)
{
    int h = blockIdx.x, n = blockIdx.y, tid = threadIdx.x;
    __shared__ float sc[LL1];
    __shared__ float red[64][33];
    float q0[32];
    const float* qp = rel + (size_t)n*1280 + 1024 + h*32;
    #pragma unroll
    for (int j = 0; j < 8; j++) {
        float4 v = *(const float4*)&qp[j*4];
        q0[j*4] = v.x; q0[j*4+1] = v.y; q0[j*4+2] = v.z; q0[j*4+3] = v.w;
    }
    for (int l = tid; l < LL1; l += 64) {
        const float* kp = (l == 0) ? (rel + (size_t)n*1280 + 512 + h*32)
                                   : (ykv + ((size_t)h*NT + n*TT + l-1)*32);
        float s = 0.f;
        #pragma unroll
        for (int j = 0; j < 8; j++) {
            float4 v = *(const float4*)&kp[j*4];
            s += q0[j*4]*v.x + q0[j*4+1]*v.y + q0[j*4+2]*v.z + q0[j*4+3]*v.w;
        }
        sc[l] = s * SCALE_F;
    }
    __syncthreads();
    float mx = -1e30f;
    for (int l = tid; l < LL1; l += 64) mx = fmaxf(mx, sc[l]);
    for (int off = 32; off; off >>= 1) mx = fmaxf(mx, __shfl_xor(mx, off));
    float sum = 0.f;
    for (int l = tid; l < LL1; l += 64) { float e = expf(sc[l]-mx); sc[l] = e; sum += e; }
    for (int off = 32; off; off >>= 1) sum += __shfl_xor(sum, off);
    __syncthreads();
    float av[32];
    #pragma unroll
    for (int d = 0; d < 32; d++) av[d] = 0.f;
    for (int l = tid; l < LL1; l += 64) {
        float e = sc[l];
        const float* vp = (l == 0) ? (rel + (size_t)n*1280 + 768 + h*32)
                                   : (ykv + ((size_t)(8+h)*NT + n*TT + l-1)*32);
        #pragma unroll
        for (int j = 0; j < 8; j++) {
            float4 v = *(const float4*)&vp[j*4];
            av[j*4] += e*v.x; av[j*4+1] += e*v.y; av[j*4+2] += e*v.z; av[j*4+3] += e*v.w;
        }
    }
    #pragma unroll
    for (int d = 0; d < 32; d++) red[tid][d] = av[d];
    __syncthreads();
    if (tid < 32) {
        float a = 0.f;
        for (int k = 0; k < 64; k++) a += red[k][tid];
        a /= sum;
        int idx = n*CC + h*32 + tid;
        out[idx] = relay[idx] + a;
    }
}

// ---------------------------------------------------------------------------
extern "C" void kernel_launch(void* const* d_in, const int* in_sizes, int n_in,
                              void* d_out, int out_size, void* d_ws, size_t ws_size,
                              hipStream_t stream)
{
    const float* data    = (const float*)d_in[0];
    const float* ln_g    = (const float*)d_in[1];
    const float* ln_b    = (const float*)d_in[2];
    const float* tj_wq   = (const float*)d_in[3];
    const float* tj_bq   = (const float*)d_in[4];
    const float* tj_wk   = (const float*)d_in[5];
    const float* tj_bk   = (const float*)d_in[6];
    const float* tj_wv   = (const float*)d_in[7];
    const float* tj_bv   = (const float*)d_in[8];
    const float* tj_bn_g = (const float*)d_in[9];
    const float* tj_bn_b = (const float*)d_in[10];
    const float* tj_w1   = (const float*)d_in[11];
    const float* tj_b1   = (const float*)d_in[12];
    const float* tj_w2   = (const float*)d_in[13];
    const float* tj_b2   = (const float*)d_in[14];
    const float* tj_fbn_g= (const float*)d_in[15];
    const float* tj_fbn_b= (const float*)d_in[16];
    const float* tr_wq   = (const float*)d_in[17];
    const float* tr_bq   = (const float*)d_in[18];
    const float* tr_wk   = (const float*)d_in[19];
    const float* tr_bk   = (const float*)d_in[20];
    const float* tr_wv   = (const float*)d_in[21];
    const float* tr_bv   = (const float*)d_in[22];
    const float* tr_bn_g = (const float*)d_in[23];
    const float* tr_bn_b = (const float*)d_in[24];
    const float* tr_w1   = (const float*)d_in[25];
    const float* tr_b1   = (const float*)d_in[26];
    const float* tr_w2   = (const float*)d_in[27];
    const float* tr_b2   = (const float*)d_in[28];
    const float* tr_fbn_g= (const float*)d_in[29];
    const float* tr_fbn_b= (const float*)d_in[30];

    const size_t SZ = (size_t)NT*CC;     // 6,553,600
    const size_t SZ_NC = (size_t)NN*CC;

    float* ws = (float*)d_ws;
    size_t off = 0;
    auto alloc = [&](size_t nf) { float* p = ws + off; off += nf; return p; };
    float*    nodesf  = alloc(SZ);          // TM f32: xln (layer0 LN in-place)
    float*    sbuf    = alloc(SZ);          // TM f32: s1 / s1b (FFN2 in-place)
    float*    P1      = alloc(SZ*5/2);      // qkv(1.5)+ekv(1.0) bf16 | h(2.0) bf16 | ykv(2.0) f32
    ushort_t* xs_bf   = (ushort_t*)alloc(SZ/2);  // xln_bf / s2_bf (TM)
    ushort_t* embs_bf = (ushort_t*)alloc(SZ/2);  // TM, persists
    ushort_t* nb_bf   = (ushort_t*)alloc(SZ/2);  // nodes bf16 (pre-LN), for ykv
    float* accs   = alloc(8*512);           // raw BN sums, 2 per layer
    float* relayA = alloc(SZ_NC);
    float* relayB = alloc(SZ_NC);
    float* rel    = alloc((size_t)NN*1280); // fused relay projections
    float* ret0   = alloc(SZ_NC);
    float* rret   = alloc(SZ_NC);
    float* ro     = alloc(SZ_NC);
    float* rh     = alloc((size_t)NN*DFFF);
    ushort_t* wqkv_bf  = (ushort_t*)alloc((size_t)ITER*768*CC/2);
    ushort_t* wkvtr_bf = (ushort_t*)alloc((size_t)ITER*512*CC/2);
    ushort_t* w1_bf    = (ushort_t*)alloc((size_t)ITER*DFFF*CC/2);
    ushort_t* w2_bf    = (ushort_t*)alloc((size_t)ITER*DFFF*CC/2);
    float* wrel  = alloc((size_t)ITER*1280*CC);
    float* brel  = alloc((size_t)ITER*1280);
    float* bqkv  = alloc((size_t)ITER*768);
    float* bkvtr = alloc((size_t)ITER*512);
    (void)ws_size; (void)in_sizes; (void)n_in; (void)out_size;

    ushort_t* qkv_tm = (ushort_t*)P1;           // HM [24][NT][32] bf16
    ushort_t* ekv_tm = qkv_tm + 3*SZ;           // HM [16][NT][32] bf16
    ushort_t* h_us   = (ushort_t*)P1;           // TM [nt][1024] bf16 (after attn)
    float*    ykv_f  = P1;                      // HM [16][NT][32] f32 (after FFN2)

    const int TCC = ITER*CC*CC, TFF = ITER*DFFF*CC;
    k_zero<<<16, 256, 0, stream>>>(accs, 8*512);
    k_cast2<<<(TCC+255)/256, 256, 0, stream>>>(tj_wq, wqkv_bf,          65536, 196608, TCC);
    k_cast2<<<(TCC+255)/256, 256, 0, stream>>>(tj_wk, wqkv_bf +  65536, 65536, 196608, TCC);
    k_cast2<<<(TCC+255)/256, 256, 0, stream>>>(tj_wv, wqkv_bf + 131072, 65536, 196608, TCC);
    k_cast2<<<(TCC+255)/256, 256, 0, stream>>>(tr_wk, wkvtr_bf,         65536, 131072, TCC);
    k_cast2<<<(TCC+255)/256, 256, 0, stream>>>(tr_wv, wkvtr_bf + 65536, 65536, 131072, TCC);
    k_cast2<<<(TFF+255)/256, 256, 0, stream>>>(tj_w1, w1_bf, TFF, TFF, TFF);
    k_cast2<<<(TFF+255)/256, 256, 0, stream>>>(tj_w2, w2_bf, TFF, TFF, TFF);
    k_copy2<<<(ITER*256+255)/256, 256, 0, stream>>>(tj_bq, bqkv,       256, 768, ITER*256);
    k_copy2<<<(ITER*256+255)/256, 256, 0, stream>>>(tj_bk, bqkv + 256, 256, 768, ITER*256);
    k_copy2<<<(ITER*256+255)/256, 256, 0, stream>>>(tj_bv, bqkv + 512, 256, 768, ITER*256);
    k_copy2<<<(ITER*256+255)/256, 256, 0, stream>>>(tr_bk, bkvtr,      256, 512, ITER*256);
    k_copy2<<<(ITER*256+255)/256, 256, 0, stream>>>(tr_bv, bkvtr+256,  256, 512, ITER*256);
    k_copy2<<<(TCC+255)/256, 256, 0, stream>>>(tj_wk, wrel,          65536, 327680, TCC);
    k_copy2<<<(TCC+255)/256, 256, 0, stream>>>(tj_wv, wrel +  65536, 65536, 327680, TCC);
    k_copy2<<<(TCC+255)/256, 256, 0, stream>>>(tr_wk, wrel + 131072, 65536, 327680, TCC);
    k_copy2<<<(TCC+255)/256, 256, 0, stream>>>(tr_wv, wrel + 196608, 65536, 327680, TCC);
    k_copy2<<<(TCC+255)/256, 256, 0, stream>>>(tr_wq, wrel + 262144, 65536, 327680, TCC);
    k_copy2<<<(ITER*256+255)/256, 256, 0, stream>>>(tj_bk, brel,        256, 1280, ITER*256);
    k_copy2<<<(ITER*256+255)/256, 256, 0, stream>>>(tj_bv, brel +  256, 256, 1280, ITER*256);
    k_copy2<<<(ITER*256+255)/256, 256, 0, stream>>>(tr_bk, brel +  512, 256, 1280, ITER*256);
    k_copy2<<<(ITER*256+255)/256, 256, 0, stream>>>(tr_bv, brel +  768, 256, 1280, ITER*256);
    k_copy2<<<(ITER*256+255)/256, 256, 0, stream>>>(tr_bq, brel + 1024, 256, 1280, ITER*256);

    k_embed<<<dim3(8, NN), 128, 0, stream>>>(data, nodesf, embs_bf, relayA);
    k_layernorm<<<NT/4, 256, 0, stream>>>(nodesf, xs_bf, ln_g, ln_b);

    float* relay = relayA;
    float* relay_next = relayB;
    dim3 sb16(16, 16);

    for (int i = 0; i < ITER; i++) {
        const size_t woff = (size_t)i*DFFF*CC;
        float* accA = accs + i*1024;
        float* accB = accs + i*1024 + 512;

        // fused relay projections: rel[n][1280] (layer3 needs only first 512)
        k_sgemm<<<dim3((i == ITER-1) ? 32 : 80, 13), sb16, 0, stream>>>(
            wrel + (size_t)i*1280*CC, relay, brel + i*1280, nullptr, rel, CC, 1280, 0);

        // merged qkv (6 n-tiles, A=xs_bf) + ekv (4 n-tiles, A=embs_bf),
        // head-major outputs. grid = 8 XCD x 13 m-tiles x ntile_tot
        k_gemm_mfma<256,0><<<104*10, 512, 0, stream>>>(
            xs_bf, wqkv_bf + (size_t)i*768*CC, bqkv + i*768,
            nullptr, nullptr, nullptr, nullptr,
            nullptr, qkv_tm, 768, 6, FL_BF16 | FL_HM,
            embs_bf, wqkv_bf + (size_t)i*768*CC + 65536, bqkv + i*768 + 256,
            ekv_tm, 512, 4, nullptr);

        // attn (zero-LDS, head-major streams)
        k_attn_tj<<<dim3(NHH, NN), 128, 0, stream>>>(qkv_tm, ekv_tm, rel, nodesf, sbuf);

        k_bnstats_tm<<<NN, 256, 0, stream>>>(sbuf, accA);
        k_bn_apply_raw<<<SZ/1024, 256, 0, stream>>>(
            sbuf, accA, tj_bn_g + i*CC, tj_bn_b + i*CC, xs_bf);

        // FFN1: h = relu(W1*s2+b1), [nt][1024] bf16 (TM)
        k_gemm_mfma<256,0><<<104*8, 512, 0, stream>>>(
            xs_bf, w1_bf + woff, tj_b1 + i*DFFF, nullptr, nullptr, nullptr, nullptr,
            nullptr, h_us, DFFF, 8, FL_RELU | FL_BF16,
            nullptr, nullptr, nullptr, nullptr, 0, 0, nullptr);
        // FFN2: sbuf = W2*h + b2 + BN1(sbuf), fused BN stats -> accB
        k_gemm_mfma<1024,1><<<104*2, 512, 0, stream>>>(
            h_us, w2_bf + woff, tj_b2 + i*CC, sbuf, accA, tj_bn_g + i*CC, tj_bn_b + i*CC,
            sbuf, nullptr, CC, 2, FL_RESBN,
            nullptr, nullptr, nullptr, nullptr, 0, 0, accB);

        if (i == ITER-1) {
            k_bn_out_t<<<dim3(NT/64, CC/64), 256, 0, stream>>>(
                sbuf, accB, tj_fbn_g + i*CC, tj_fbn_b + i*CC, (float*)d_out);
            break;   // last relay update is dead code
        }
        // fused BN2+leaky+LN(i+1): nodes_bf + xln f32 + xln bf16
        k_bn_ln<<<NT/4, 256, 0, stream>>>(
            sbuf, accB, tj_fbn_g + i*CC, tj_fbn_b + i*CC,
            ln_g + (i+1)*CC, ln_b + (i+1)*CC, nodesf, xs_bf, nb_bf);

        // relay path: ykv = W_kv^tr * nodes, head-major f32
        k_gemm_mfma<256,0><<<104*4, 512, 0, stream>>>(
            nb_bf, wkvtr_bf + (size_t)i*512*CC, bkvtr + i*512,
            nullptr, nullptr, nullptr, nullptr,
            ykv_f, nullptr, 512, 4, FL_HM,
            nullptr, nullptr, nullptr, nullptr, 0, 0, nullptr);

        k_attn_tr<<<dim3(NHH, NN), 64, 0, stream>>>(rel, ykv_f, relay, ret0);
        k_bn_relay<<<CC, 64, 0, stream>>>(ret0, rret, tr_bn_g + i*CC, tr_bn_b + i*CC, 0);

        k_sgemm<<<dim3(DFFF/16, (NN+15)/16), sb16, 0, stream>>>(
            tr_w1 + woff, rret, tr_b1 + i*DFFF, nullptr, rh, CC, DFFF, 1);
        k_sgemm<<<dim3(16, (NN+15)/16), sb16, 0, stream>>>(
            tr_w2 + woff, rh, tr_b2 + i*CC, rret, ro, DFFF, CC, 0);
        k_bn_relay<<<CC, 64, 0, stream>>>(ro, relay_next, tr_fbn_g + i*CC, tr_fbn_b + i*CC, 1);

        float* tmp = relay; relay = relay_next; relay_next = tmp;
    }
}

// Round 12
// 1122.559 us; speedup vs baseline: 1.0878x; 1.0878x over previous
//
#include <hip/hip_runtime.h>
#include <cstddef>

#define BB   8
#define VV   25
#define TT   128
#define CC   256
#define NHH  8
#define DKK  32
#define DFFF 1024
#define ITER 4
#define NN   (BB*VV)     // 200
#define NT   (NN*TT)     // 25600
#define LL1  (TT+1)      // 129
#define EPS_LN 1e-6f
#define EPS_BN 1e-5f
#define SLOPE  0.01f
#define SCALE_F 0.17677669529663687f   // 1/sqrt(32)

typedef unsigned short ushort_t;
typedef __attribute__((ext_vector_type(8))) short short8;
typedef __attribute__((ext_vector_type(4))) short short4_t;
typedef __attribute__((ext_vector_type(4))) float floatx4;

union U8 { short8 v; ushort_t u[8]; };

__device__ __forceinline__ float bf2f(ushort_t u) {
    union { unsigned int i; float f; } x; x.i = ((unsigned int)u) << 16; return x.f;
}
__device__ __forceinline__ ushort_t f2bf(float f) {
    union { float f; unsigned int i; } x; x.f = f;
    unsigned int r = x.i + 0x7FFFu + ((x.i >> 16) & 1u);   // RNE
    return (ushort_t)(r >> 16);
}
// finalize raw BN sums -> (mean, rstd)
__device__ __forceinline__ float2 bn_fin(float s, float ss) {
    float m = s * (1.0f/NT);
    float var = ss * (1.0f/NT) - m*m; if (var < 0.f) var = 0.f;
    return make_float2(m, rsqrtf(var + EPS_BN));
}

// async global->LDS, 16B per lane (dest must be wave-uniform base; HW adds lane*16)
__device__ __forceinline__ void gl_lds16(const ushort_t* g, ushort_t* l) {
    __builtin_amdgcn_global_load_lds(
        (const __attribute__((address_space(1))) unsigned int*)g,
        (__attribute__((address_space(3))) unsigned int*)l,
        16, 0, 0);
}

// load 32 bf16 (contiguous) -> f32 regs
__device__ __forceinline__ void ld32(const ushort_t* p, float* q) {
    #pragma unroll
    for (int c8 = 0; c8 < 4; c8++) {
        U8 u; u.v = *(const short8*)(p + c8*8);
        #pragma unroll
        for (int j = 0; j < 8; j++) q[c8*8+j] = bf2f(u.u[j]);
    }
}
__device__ __forceinline__ float dot32(const ushort_t* p, const float* q) {
    float s = 0.f;
    #pragma unroll
    for (int c8 = 0; c8 < 4; c8++) {
        U8 u; u.v = *(const short8*)(p + c8*8);
        #pragma unroll
        for (int j = 0; j < 8; j++) s += q[c8*8+j]*bf2f(u.u[j]);
    }
    return s;
}
__device__ __forceinline__ void acc32(const ushort_t* p, float e, float* av) {
    #pragma unroll
    for (int c8 = 0; c8 < 4; c8++) {
        U8 u; u.v = *(const short8*)(p + c8*8);
        #pragma unroll
        for (int j = 0; j < 8; j++) av[c8*8+j] += e*bf2f(u.u[j]);
    }
}

// ---------------------------------------------------------------------------
// R17 prologue fusion: 21 setup micro-launches -> 4.
// k_prep_w: all weight casts/copies (10 jobs x TCC elems, job = blockIdx>>10).
// Byte-identical indexing to the old per-job k_cast2/k_copy2 calls.
__global__ __launch_bounds__(256) void k_prep_w(
    const float* __restrict__ tj_wq, const float* __restrict__ tj_wk,
    const float* __restrict__ tj_wv, const float* __restrict__ tr_wk,
    const float* __restrict__ tr_wv, const float* __restrict__ tr_wq,
    ushort_t* __restrict__ wqkv, ushort_t* __restrict__ wkvtr,
    float* __restrict__ wrel)
{
    int j = blockIdx.x >> 10;
    int i = (int)(blockIdx.x & 1023)*256 + threadIdx.x;   // 0..262143
    int l = i >> 16, off = i & 65535;
    switch (j) {
        case 0: wqkv[(size_t)l*196608 +      0 + off] = f2bf(tj_wq[i]); break;
        case 1: wqkv[(size_t)l*196608 +  65536 + off] = f2bf(tj_wk[i]); break;
        case 2: wqkv[(size_t)l*196608 + 131072 + off] = f2bf(tj_wv[i]); break;
        case 3: wkvtr[(size_t)l*131072 +     0 + off] = f2bf(tr_wk[i]); break;
        case 4: wkvtr[(size_t)l*131072 + 65536 + off] = f2bf(tr_wv[i]); break;
        case 5: wrel[(size_t)l*327680 +      0 + off] = tj_wk[i]; break;
        case 6: wrel[(size_t)l*327680 +  65536 + off] = tj_wv[i]; break;
        case 7: wrel[(size_t)l*327680 + 131072 + off] = tr_wk[i]; break;
        case 8: wrel[(size_t)l*327680 + 196608 + off] = tr_wv[i]; break;
        default: wrel[(size_t)l*327680 + 262144 + off] = tr_wq[i]; break;
    }
}
// k_prep_small: accs zero (blocks 0-15) + 10 bias strided copies (blocks
// 16-55, 4 blocks/job, 1024 elems each).
__global__ __launch_bounds__(256) void k_prep_small(
    const float* __restrict__ tj_bq, const float* __restrict__ tj_bk,
    const float* __restrict__ tj_bv, const float* __restrict__ tr_bq,
    const float* __restrict__ tr_bk, const float* __restrict__ tr_bv,
    float* __restrict__ bqkv, float* __restrict__ bkvtr,
    float* __restrict__ brel, float* __restrict__ accs)
{
    int b = blockIdx.x, tid = threadIdx.x;
    if (b < 16) { accs[b*256 + tid] = 0.f; return; }
    int j = (b - 16) >> 2;
    int i = ((b - 16) & 3)*256 + tid;       // 0..1023
    int l = i >> 8, off = i & 255;
    const float* src; float* dst; int dstride, doff;
    switch (j) {
        case 0: src=tj_bq; dst=bqkv;  dstride=768;  doff=0;    break;
        case 1: src=tj_bk; dst=bqkv;  dstride=768;  doff=256;  break;
        case 2: src=tj_bv; dst=bqkv;  dstride=768;  doff=512;  break;
        case 3: src=tr_bk; dst=bkvtr; dstride=512;  doff=0;    break;
        case 4: src=tr_bv; dst=bkvtr; dstride=512;  doff=256;  break;
        case 5: src=tj_bk; dst=brel;  dstride=1280; doff=0;    break;
        case 6: src=tj_bv; dst=brel;  dstride=1280; doff=256;  break;
        case 7: src=tr_bk; dst=brel;  dstride=1280; doff=512;  break;
        case 8: src=tr_bv; dst=brel;  dstride=1280; doff=768;  break;
        default: src=tr_bq; dst=brel; dstride=1280; doff=1024; break;
    }
    dst[l*dstride + doff + off] = src[i];
}
// strided cast (kept for w1/w2)
__global__ __launch_bounds__(256) void k_cast2(const float* __restrict__ src,
    ushort_t* __restrict__ dst, int per, int dstride, int total)
{
    int i = blockIdx.x*256 + threadIdx.x;
    if (i < total) dst[(size_t)(i/per)*dstride + (i%per)] = f2bf(src[i]);
}

// ---------------------------------------------------------------------------
// embed: nodesf[nt][c] f32 TM + embs_bf TM + relay[n][c]=mean_t. LDS transpose.
__global__ __launch_bounds__(128) void k_embed(const float* __restrict__ data,
    float* __restrict__ nodesf, ushort_t* __restrict__ embs_bf, float* __restrict__ relay)
{
    __shared__ float tile[32][TT+1];
    int cc0 = blockIdx.x*32, n = blockIdx.y;
    int b = n / VV, v = n % VV, t = threadIdx.x;
    for (int cl = 0; cl < 32; cl++)
        tile[cl][t] = data[(((size_t)b*CC + cc0 + cl)*VV + v)*TT + t];
    __syncthreads();
    if (t < 32) {
        float s = 0.f;
        for (int tt = 0; tt < TT; tt++) s += tile[t][tt];
        relay[n*CC + cc0 + t] = s * (1.0f/TT);
    }
    #pragma unroll 8
    for (int it = 0; it < 32; it++) {
        int t_l = it*4 + (t >> 5), c_l = t & 31;
        float val = tile[c_l][t_l];
        size_t o = (size_t)(n*TT + t_l)*CC + cc0 + c_l;
        nodesf[o] = val;
        embs_bf[o] = f2bf(val);
    }
}

// ---------------------------------------------------------------------------
// LayerNorm TM in-place + bf16 TM copy. One wave per token. (layer 0 only)
__global__ __launch_bounds__(256) void k_layernorm(float* __restrict__ x,
    ushort_t* __restrict__ outb, const float* __restrict__ g, const float* __restrict__ b)
{
    int wave = threadIdx.x >> 6, lane = threadIdx.x & 63;
    size_t base = (size_t)(blockIdx.x*4 + wave)*CC + lane*4;
    float4 v = *(float4*)&x[base];
    float s  = v.x + v.y + v.z + v.w;
    float ss = v.x*v.x + v.y*v.y + v.z*v.z + v.w*v.w;
    #pragma unroll
    for (int o = 32; o; o >>= 1) { s += __shfl_xor(s, o); ss += __shfl_xor(ss, o); }
    float m = s * (1.0f/CC);
    float var = ss * (1.0f/CC) - m*m; if (var < 0.f) var = 0.f;
    float rs = rsqrtf(var + EPS_LN);
    float4 gg = *(const float4*)&g[lane*4];
    float4 bb = *(const float4*)&b[lane*4];
    v.x = (v.x - m)*rs*gg.x + bb.x;
    v.y = (v.y - m)*rs*gg.y + bb.y;
    v.z = (v.z - m)*rs*gg.z + bb.z;
    v.w = (v.w - m)*rs*gg.w + bb.w;
    *(float4*)&x[base] = v;
    ushort_t o4[4] = {f2bf(v.x), f2bf(v.y), f2bf(v.z), f2bf(v.w)};
    *(short4_t*)&outb[base] = *(short4_t*)o4;
}

// ---------------------------------------------------------------------------
// bf16 MFMA GEMM. R15 verified-best core: 512 threads / 8 waves per 128x128
// tile; triple-buffered 48KB (3 blocks/CU), counted vmcnt(2). Each wave:
// 64x32 sub-tile, 8 MFMA + 6 ds_read_b128 per phase; waves 0-3 stage the
// A-tile, 4-7 the B-tile (2 x gl_lds16 each). R8 swapped-operand MFMA +
// vectorized epilogue; R10 DUAL-JOB + STATS; R11 FL_HM head-major output.
#define FL_RELU  1
#define FL_BF16  2
#define FL_RESBN 4
#define FL_HM    8

#define STAGE(SA, SB, T_) do {                                              \
    ushort_t* db_ = isA ? (SA) : (SB);                                      \
    gl_lds16(gSrc[0] + (T_)*32, &db_[dstOff[0]]);                           \
    gl_lds16(gSrc[1] + (T_)*32, &db_[dstOff[1]]);                           \
    } while (0)

// swapped operand order: mfma(B_frag, A_frag, acc) -> transposed fragment:
// lane holds m = ...+fc (fixed), n = ...+fr*4+r (4 consecutive).
#define COMPUTE(SA, SB) do {                                                \
    short8 af_[4], bf_[2];                                                  \
    _Pragma("unroll")                                                       \
    for (int mi_ = 0; mi_ < 4; mi_++)                                       \
        af_[mi_] = *(const short8*)&SA[aOff[mi_]];                          \
    _Pragma("unroll")                                                       \
    for (int ni_ = 0; ni_ < 2; ni_++)                                       \
        bf_[ni_] = *(const short8*)&SB[bOff[ni_]];                          \
    _Pragma("unroll")                                                       \
    for (int mi_ = 0; mi_ < 4; mi_++)                                       \
        _Pragma("unroll")                                                   \
        for (int ni_ = 0; ni_ < 2; ni_++)                                   \
            acc[mi_][ni_] = __builtin_amdgcn_mfma_f32_16x16x32_bf16(        \
                bf_[ni_], af_[mi_], acc[mi_][ni_], 0, 0, 0);                \
    } while (0)

#define WAITVL(S_) asm volatile("s_waitcnt vmcnt(" S_ ") lgkmcnt(0)" ::: "memory")

// phase t: prefetch tile t+2; compute tile t; counted wait for tile t+1
// (this wave's t+2 batch of 2 stays in flight); barrier.
#define PHASE(CA, CB, PA, PB, T_) do {                                      \
    if ((T_) + 2 < NK) STAGE(PA, PB, (T_) + 2);                             \
    COMPUTE(CA, CB);                                                        \
    if ((T_) + 1 < NK) {                                                    \
        __builtin_amdgcn_sched_barrier(0);                                  \
        if ((T_) + 2 < NK) WAITVL("2");                                     \
        else               WAITVL("0");                                     \
        __builtin_amdgcn_s_barrier();                                       \
        __builtin_amdgcn_sched_barrier(0);                                  \
    }                                                                       \
    } while (0)

template<int K, int STATS>
__global__ __launch_bounds__(512) void k_gemm_mfma(
    const ushort_t* A, const ushort_t* B, const float* bias,
    const float* rx, const float* __restrict__ rawms,
    const float* __restrict__ bng, const float* __restrict__ bnb,
    float* outf, ushort_t* outb, int ostride, int ntiles_n, int flags,
    const ushort_t* A2, const ushort_t* B2, const float* bias2,
    ushort_t* outb2, int ostride2, int ntiles_n2,
    float* stats_acc)
{
    __shared__ ushort_t sA0[128*32];
    __shared__ ushort_t sB0[128*32];
    __shared__ ushort_t sA1[128*32];
    __shared__ ushort_t sB1[128*32];
    __shared__ ushort_t sA2[128*32];
    __shared__ ushort_t sB2[128*32];
    const int pid = blockIdx.x;
    const int xcd = pid & 7, idx = pid >> 3;
    const int ntile_tot = ntiles_n + ntiles_n2;
    const int nt_i = idx % ntile_tot;
    const int m0 = (xcd*25 + idx/ntile_tot) * 128;   // 200 m-tiles = 8 XCD x 25
    // job select (wave-uniform)
    const ushort_t* Ap;  const ushort_t* Bp;  const float* biasp;
    ushort_t* outbp;  int ostridep, n0;
    if (nt_i < ntiles_n) {
        Ap = A;  Bp = B;  biasp = bias;  outbp = outb;
        ostridep = ostride;  n0 = nt_i*128;
    } else {
        Ap = A2; Bp = B2; biasp = bias2; outbp = outb2;
        ostridep = ostride2; n0 = (nt_i - ntiles_n)*128;
    }
    const int tid = threadIdx.x;
    const int lane = tid & 63, wave = tid >> 6;      // 0..7
    const int wm = (wave & 1) * 64, wn = (wave >> 1) * 32;
    const int fr = lane >> 4, fc = lane & 15;

    // staging: 16 x 1KB slots per phase (A: slots 0-7, B: 8-15);
    // wave w owns slots {2w, 2w+1}. chunk (row,kc) at LDS slot
    // row*4 + ((kc + (row>>1)) & 3); inverse gives global src per lane.
    const bool isA = (wave < 4);
    const ushort_t* gSrc[2];
    int dstOff[2];
    #pragma unroll
    for (int j = 0; j < 2; j++) {
        int s  = wave*2 + j;
        int sl = isA ? s : s - 8;
        int c  = sl*64 + lane;
        int row = c >> 2;
        int kcs = ((c & 3) - (row >> 1)) & 3;
        gSrc[j] = (isA ? Ap + (size_t)(m0 + row)*K
                       : Bp + (size_t)(n0 + row)*K) + kcs*8;
        dstOff[j] = sl*512;                        // wave-uniform (16B slots)
    }
    // ds_read fragment offsets (ushorts), loop-invariant
    int aOff[4], bOff[2];
    #pragma unroll
    for (int mi = 0; mi < 4; mi++) {
        int row = wm + mi*16 + fc;
        aOff[mi] = row*32 + (((fr + (row >> 1)) & 3) * 8);
    }
    #pragma unroll
    for (int ni = 0; ni < 2; ni++) {
        int row = wn + ni*16 + fc;
        bOff[ni] = row*32 + (((fr + (row >> 1)) & 3) * 8);
    }

    floatx4 acc[4][2];
    #pragma unroll
    for (int i = 0; i < 4; i++)
        #pragma unroll
        for (int j = 0; j < 2; j++) acc[i][j] = (floatx4){0.f,0.f,0.f,0.f};

    constexpr int NK = K >> 5;
    // prologue: tiles 0,1 in flight; wait for tile 0 (this wave: vmcnt(2))
    STAGE(sA0, sB0, 0);
    if (NK > 1) STAGE(sA1, sB1, 1);
    __builtin_amdgcn_sched_barrier(0);
    if (NK > 1) WAITVL("2");
    else        WAITVL("0");
    __builtin_amdgcn_s_barrier();
    __builtin_amdgcn_sched_barrier(0);

    #pragma unroll
    for (int tb = 0; tb < NK; tb += 3) {
        PHASE(sA0, sB0, sA2, sB2, tb);
        if (tb + 1 < NK) PHASE(sA1, sB1, sA0, sB0, tb + 1);
        if (tb + 2 < NK) PHASE(sA2, sB2, sA1, sB1, tb + 2);
    }

    // Epilogue: lane (fr,fc) of acc[mi][ni] holds
    // m = m0+wm+mi*16+fc, n = n0+wn+ni*16+fr*4 + r, r=0..3 consecutive.
    float st[2][4], sst[2][4];
    if constexpr (STATS) {
        #pragma unroll
        for (int a = 0; a < 2; a++)
            #pragma unroll
            for (int b2_ = 0; b2_ < 4; b2_++) { st[a][b2_] = 0.f; sst[a][b2_] = 0.f; }
    }
    #pragma unroll
    for (int ni = 0; ni < 2; ni++) {
        int nb = n0 + wn + ni*16 + fr*4;
        float4 bias4 = *(const float4*)&biasp[nb];
        float bm[4] = {0,0,0,0}, bs[4] = {0,0,0,0}, bb2[4] = {0,0,0,0};
        if (flags & FL_RESBN) {
            float4 s1 = *(const float4*)&rawms[nb];
            float4 s2 = *(const float4*)&rawms[CC + nb];
            float4 g4 = *(const float4*)&bng[nb];
            float4 b4 = *(const float4*)&bnb[nb];
            float2 f0 = bn_fin(s1.x, s2.x); float2 f1 = bn_fin(s1.y, s2.y);
            float2 f2 = bn_fin(s1.z, s2.z); float2 f3 = bn_fin(s1.w, s2.w);
            bm[0]=f0.x; bm[1]=f1.x; bm[2]=f2.x; bm[3]=f3.x;
            bs[0]=f0.y*g4.x; bs[1]=f1.y*g4.y; bs[2]=f2.y*g4.z; bs[3]=f3.y*g4.w;
            bb2[0]=b4.x; bb2[1]=b4.y; bb2[2]=b4.z; bb2[3]=b4.w;
        }
        float bia[4] = {bias4.x, bias4.y, bias4.z, bias4.w};
        // head-major base: ((nb>>5)*NT + m)*32 + (nb&31)
        size_t hm_base = ((size_t)(nb >> 5) * NT) * 32 + (nb & 31);
        #pragma unroll
        for (int mi = 0; mi < 4; mi++) {
            int m = m0 + wm + mi*16 + fc;
            size_t idx2 = (flags & FL_HM) ? hm_base + (size_t)m*32
                                          : (size_t)m*ostridep + nb;
            float vals[4];
            #pragma unroll
            for (int r = 0; r < 4; r++) vals[r] = acc[mi][ni][r] + bia[r];
            if (flags & FL_RESBN) {
                float4 rx4 = *(const float4*)&rx[idx2];
                float rxa[4] = {rx4.x, rx4.y, rx4.z, rx4.w};
                #pragma unroll
                for (int r = 0; r < 4; r++)
                    vals[r] += (rxa[r] - bm[r])*bs[r] + bb2[r];
            }
            if (flags & FL_RELU)
                #pragma unroll
                for (int r = 0; r < 4; r++) vals[r] = fmaxf(vals[r], 0.f);
            if constexpr (STATS) {
                #pragma unroll
                for (int r = 0; r < 4; r++) {
                    st[ni][r] += vals[r];
                    sst[ni][r] += vals[r]*vals[r];
                }
            }
            if (flags & FL_BF16) {
                ushort_t o4[4] = {f2bf(vals[0]), f2bf(vals[1]),
                                  f2bf(vals[2]), f2bf(vals[3])};
                *(short4_t*)&outbp[idx2] = *(short4_t*)o4;
            } else {
                float4 ov = make_float4(vals[0], vals[1], vals[2], vals[3]);
                *(float4*)&outf[idx2] = ov;
            }
        }
    }
    if constexpr (STATS) {
        // reduce over the 16 fc lanes (same channel set), then atomicAdd
        #pragma unroll
        for (int ni = 0; ni < 2; ni++)
            #pragma unroll
            for (int r = 0; r < 4; r++) {
                float s_ = st[ni][r], ss_ = sst[ni][r];
                #pragma unroll
                for (int msk = 1; msk < 16; msk <<= 1) {
                    s_  += __shfl_xor(s_,  msk);
                    ss_ += __shfl_xor(ss_, msk);
                }
                st[ni][r] = s_; sst[ni][r] = ss_;
            }
        if (fc == 0) {
            #pragma unroll
            for (int ni = 0; ni < 2; ni++)
                #pragma unroll
                for (int r = 0; r < 4; r++) {
                    int ch = n0 + wn + ni*16 + fr*4 + r;
                    atomicAdd(&stats_acc[ch],      st[ni][r]);
                    atomicAdd(&stats_acc[CC + ch], sst[ni][r]);
                }
        }
    }
}

// ---------------------------------------------------------------------------
// Small fp32 GEMM (relay path). R9 core: one barrier pair per 256-wide
// K-chunk, float4 staging + ds_read_b128 dot product.
__global__ __launch_bounds__(256) void k_sgemm(
    const float* __restrict__ W, const float* __restrict__ X,
    const float* __restrict__ bias, const float* __restrict__ res,
    float* __restrict__ out, int K, int OUT, int do_relu)
{
    __shared__ float sW[16][260];
    __shared__ float sX[16][260];
    int o0 = blockIdx.x*16, n0 = blockIdx.y*16;
    int tx = threadIdx.x, ty = threadIdx.y;
    int tid = ty*16 + tx;
    float acc0 = 0.f, acc1 = 0.f;
    for (int kc = 0; kc < K; kc += 256) {
        #pragma unroll
        for (int j = 0; j < 4; j++) {
            int lin = tid + j*256;
            int row = lin >> 6, c4 = (lin & 63)*4;
            *(float4*)&sW[row][c4] = *(const float4*)&W[(size_t)(o0+row)*K + kc + c4];
            float4 xv = make_float4(0.f,0.f,0.f,0.f);
            if (n0 + row < NN) xv = *(const float4*)&X[(size_t)(n0+row)*K + kc + c4];
            *(float4*)&sX[row][c4] = xv;
        }
        __syncthreads();
        #pragma unroll 8
        for (int k4 = 0; k4 < 64; k4 += 2) {
            float4 w0 = *(const float4*)&sW[tx][k4*4];
            float4 x0 = *(const float4*)&sX[ty][k4*4];
            float4 w1 = *(const float4*)&sW[tx][k4*4+4];
            float4 x1 = *(const float4*)&sX[ty][k4*4+4];
            acc0 += w0.x*x0.x + w0.y*x0.y + w0.z*x0.z + w0.w*x0.w;
            acc1 += w1.x*x1.x + w1.y*x1.y + w1.z*x1.z + w1.w*x1.w;
        }
        __syncthreads();
    }
    float accv = acc0 + acc1;
    int o = o0 + tx, n = n0 + ty;
    if (n < NN) {
        float val = accv + bias[o];
        if (res) val += res[(size_t)n*OUT + o];
        if (do_relu) val = fmaxf(val, 0.f);
        out[(size_t)n*OUT + o] = val;
    }
}

// ---------------------------------------------------------------------------
// tj attention, HEAD-MAJOR inputs (R11): qkv [24 heads][NT][32] bf16
// (q:0-7, k:8-15, v:16-23), ekv [16][NT][32] bf16 (ek:0-7, ev:8-15).
// rel [n][1280] f32, xln [nt][256] f32. Zero LDS — occupancy carries it.
__global__ __launch_bounds__(128) void k_attn_tj(
    const ushort_t* __restrict__ qkv, const ushort_t* __restrict__ ekv,
    const float* __restrict__ rel, const float* __restrict__ xln,
    float* __restrict__ out)
{
    int t = threadIdx.x, h = blockIdx.x, n = blockIdx.y;
    int nt = n*TT + t;
    const ushort_t* qp = qkv + ((size_t)h*NT       + nt)*32;
    const ushort_t* kp = qkv + ((size_t)(8+h)*NT   + nt)*32;
    const ushort_t* vp = qkv + ((size_t)(16+h)*NT  + nt)*32;
    const ushort_t* ep = ekv + ((size_t)h*NT       + nt)*32;
    const ushort_t* evp= ekv + ((size_t)(8+h)*NT   + nt)*32;
    const float*    rp = rel + n*1280 + h*32;   // k at +0, v at +256

    float qv[32];
    ld32(qp, qv);
    float s0 = 0.f, s1, s2 = 0.f, s3, s4 = 0.f;
    s1 = dot32(kp, qv);
    s3 = dot32(ep, qv);
    #pragma unroll
    for (int j = 0; j < 8; j++) {
        float4 rv4 = *(const float4*)&rp[j*4];
        s4 += qv[j*4]*rv4.x + qv[j*4+1]*rv4.y + qv[j*4+2]*rv4.z + qv[j*4+3]*rv4.w;
    }
    if (t > 0)    s0 = dot32(kp - 32, qv);
    if (t < TT-1) s2 = dot32(kp + 32, qv);

    s0 *= SCALE_F; s1 *= SCALE_F; s2 *= SCALE_F; s3 *= SCALE_F; s4 *= SCALE_F;
    float mx = fmaxf(fmaxf(fmaxf(s0, s1), fmaxf(s2, s3)), s4);
    float e0 = expf(s0-mx), e1 = expf(s1-mx), e2 = expf(s2-mx), e3 = expf(s3-mx), e4 = expf(s4-mx);
    float inv = 1.f/(e0+e1+e2+e3+e4);
    e0 *= inv; e1 *= inv; e2 *= inv; e3 *= inv; e4 *= inv;

    float av[32];
    #pragma unroll
    for (int d = 0; d < 32; d++) av[d] = 0.f;
    acc32(vp, e1, av);
    acc32(evp, e3, av);
    if (t > 0)    acc32(vp - 32, e0, av);
    if (t < TT-1) acc32(vp + 32, e2, av);
    #pragma unroll
    for (int j = 0; j < 8; j++) {
        float4 rv4 = *(const float4*)&rp[256 + j*4];
        av[j*4] += e4*rv4.x; av[j*4+1] += e4*rv4.y; av[j*4+2] += e4*rv4.z; av[j*4+3] += e4*rv4.w;
    }
    const float* xp = xln + (size_t)nt*CC + h*32;
    float* op = out + (size_t)nt*CC + h*32;
    #pragma unroll
    for (int j = 0; j < 8; j++) {
        float4 xv = *(const float4*)&xp[j*4];
        float4 ov;
        ov.x = xv.x + av[j*4]; ov.y = xv.y + av[j*4+1];
        ov.z = xv.z + av[j*4+2]; ov.w = xv.w + av[j*4+3];
        *(float4*)&op[j*4] = ov;
    }
}

// ---------------------------------------------------------------------------
// BN stats over tokens, TM input; atomicAdd raw sums into accum[512]
// (accum must be zeroed earlier in this launch).
__global__ __launch_bounds__(256) void k_bnstats_tm(const float* __restrict__ x,
    float* __restrict__ accum)
{
    __shared__ float lds[8][256];
    int w = threadIdx.x >> 6, lane = threadIdx.x & 63;
    size_t base = (size_t)blockIdx.x*TT*CC;
    float s[4] = {0,0,0,0}, ss[4] = {0,0,0,0};
    for (int tok = w; tok < TT; tok += 4) {
        float4 v = *(const float4*)&x[base + (size_t)tok*CC + lane*4];
        s[0] += v.x; s[1] += v.y; s[2] += v.z; s[3] += v.w;
        ss[0] += v.x*v.x; ss[1] += v.y*v.y; ss[2] += v.z*v.z; ss[3] += v.w*v.w;
    }
    #pragma unroll
    for (int j = 0; j < 4; j++) { lds[w][lane*4+j] = s[j]; lds[4+w][lane*4+j] = ss[j]; }
    __syncthreads();
    int c = threadIdx.x;
    float ps  = lds[0][c]+lds[1][c]+lds[2][c]+lds[3][c];
    float pss = lds[4][c]+lds[5][c]+lds[6][c]+lds[7][c];
    atomicAdd(&accum[c], ps);
    atomicAdd(&accum[CC + c], pss);
}

// ---------------------------------------------------------------------------
// BN1 apply (no leaky), raw sums, bf16 TM out only
__global__ __launch_bounds__(256) void k_bn_apply_raw(const float* __restrict__ x,
    const float* __restrict__ acc, const float* __restrict__ g, const float* __restrict__ b,
    ushort_t* __restrict__ outb)
{
    size_t base = ((size_t)blockIdx.x*256 + threadIdx.x)*4;
    int c0 = (int)(base & (CC-1));
    float4 v  = *(const float4*)&x[base];
    float4 a1 = *(const float4*)&acc[c0];
    float4 a2 = *(const float4*)&acc[CC + c0];
    float4 g4 = *(const float4*)&g[c0];
    float4 b4 = *(const float4*)&b[c0];
    float vals[4] = {v.x,v.y,v.z,v.w};
    float s1v[4] = {a1.x,a1.y,a1.z,a1.w};
    float s2v[4] = {a2.x,a2.y,a2.z,a2.w};
    float gg[4] = {g4.x,g4.y,g4.z,g4.w};
    float bb[4] = {b4.x,b4.y,b4.z,b4.w};
    ushort_t o4[4];
    #pragma unroll
    for (int j = 0; j < 4; j++) {
        float2 f = bn_fin(s1v[j], s2v[j]);
        o4[j] = f2bf((vals[j] - f.x)*f.y*gg[j] + bb[j]);
    }
    *(short4_t*)&outb[base] = *(short4_t*)o4;
}

// Fused BN2 + leaky + next-layer LN. One wave/token.
__global__ __launch_bounds__(256) void k_bn_ln(const float* __restrict__ x,
    const float* __restrict__ acc, const float* __restrict__ fg, const float* __restrict__ fb,
    const float* __restrict__ lg, const float* __restrict__ lb,
    float* __restrict__ xlnf, ushort_t* __restrict__ xlnb, ushort_t* __restrict__ nodesb)
{
    int wave = threadIdx.x >> 6, lane = threadIdx.x & 63;
    int c0 = lane*4;
    size_t base = (size_t)(blockIdx.x*4 + wave)*CC + c0;
    float4 v  = *(const float4*)&x[base];
    float4 a1 = *(const float4*)&acc[c0];
    float4 a2 = *(const float4*)&acc[CC + c0];
    float4 g4 = *(const float4*)&fg[c0];
    float4 b4 = *(const float4*)&fb[c0];
    float vals[4] = {v.x,v.y,v.z,v.w};
    float s1v[4] = {a1.x,a1.y,a1.z,a1.w};
    float s2v[4] = {a2.x,a2.y,a2.z,a2.w};
    float gg[4] = {g4.x,g4.y,g4.z,g4.w};
    float bb[4] = {b4.x,b4.y,b4.z,b4.w};
    ushort_t nb4[4];
    #pragma unroll
    for (int j = 0; j < 4; j++) {
        float2 f = bn_fin(s1v[j], s2v[j]);
        float vv = (vals[j] - f.x)*f.y*gg[j] + bb[j];
        vv = vv > 0.f ? vv : SLOPE*vv;
        vals[j] = vv;
        nb4[j] = f2bf(vv);
    }
    *(short4_t*)&nodesb[base] = *(short4_t*)nb4;
    float s  = vals[0]+vals[1]+vals[2]+vals[3];
    float ss = vals[0]*vals[0]+vals[1]*vals[1]+vals[2]*vals[2]+vals[3]*vals[3];
    #pragma unroll
    for (int o = 32; o; o >>= 1) { s += __shfl_xor(s, o); ss += __shfl_xor(ss, o); }
    float m = s * (1.0f/CC);
    float var = ss * (1.0f/CC) - m*m; if (var < 0.f) var = 0.f;
    float rs = rsqrtf(var + EPS_LN);
    float4 lg4 = *(const float4*)&lg[c0];
    float4 lb4 = *(const float4*)&lb[c0];
    float lgv[4] = {lg4.x,lg4.y,lg4.z,lg4.w};
    float lbv[4] = {lb4.x,lb4.y,lb4.z,lb4.w};
    float4 xo;
    ushort_t xb4[4];
    float t0 = (vals[0]-m)*rs*lgv[0] + lbv[0];
    float t1 = (vals[1]-m)*rs*lgv[1] + lbv[1];
    float t2 = (vals[2]-m)*rs*lgv[2] + lbv[2];
    float t3 = (vals[3]-m)*rs*lgv[3] + lbv[3];
    xo.x = t0; xo.y = t1; xo.z = t2; xo.w = t3;
    xb4[0]=f2bf(t0); xb4[1]=f2bf(t1); xb4[2]=f2bf(t2); xb4[3]=f2bf(t3);
    *(float4*)&xlnf[base] = xo;
    *(short4_t*)&xlnb[base] = *(short4_t*)xb4;
}

// final BN + leaky + transpose TM -> d_out [n][c][t], raw sums
__global__ __launch_bounds__(256) void k_bn_out_t(const float* __restrict__ x,
    const float* __restrict__ acc, const float* __restrict__ g, const float* __restrict__ b,
    float* __restrict__ out)
{
    __shared__ float tile[64][65];
    int nt0 = blockIdx.x*64, c0 = blockIdx.y*64;
    int w = threadIdx.x >> 6, lane = threadIdx.x & 63;
    int n = nt0 >> 7, t0 = nt0 & 127;
    int c = c0 + lane;
    float2 f = bn_fin(acc[c], acc[CC + c]);
    float gg = f.y*g[c], mm = f.x, bb = b[c];
    #pragma unroll
    for (int it = 0; it < 16; it++) {
        int tok = it*4 + w;
        float v = x[(size_t)(nt0 + tok)*CC + c];
        v = (v - mm)*gg + bb;
        v = v > 0.f ? v : SLOPE*v;
        tile[tok][lane] = v;
    }
    __syncthreads();
    #pragma unroll
    for (int it = 0; it < 16; it++) {
        int c_l = it*4 + w;
        out[(size_t)(n*CC + c0 + c_l)*TT + t0 + lane] = tile[lane][c_l];
    }
}

// BatchNorm over n only (relay path), x/out [N,C]
__global__ __launch_bounds__(64) void k_bn_relay(const float* __restrict__ x,
    float* __restrict__ out, const float* __restrict__ g, const float* __restrict__ b, int leaky)
{
    int c = blockIdx.x, tid = threadIdx.x;
    float s = 0.f, ss = 0.f;
    for (int n = tid; n < NN; n += 64) { float v = x[(size_t)n*CC + c]; s += v; ss += v*v; }
    for (int off = 32; off; off >>= 1) { s += __shfl_down(s, off); ss += __shfl_down(ss, off); }
    float S = __shfl(s, 0), SS = __shfl(ss, 0);
    float m = S / NN;
    float var = SS / NN - m*m; if (var < 0.f) var = 0.f;
    float rs = rsqrtf(var + EPS_BN);
    float gg = g[c]*rs, bb = b[c];
    for (int n = tid; n < NN; n += 64) {
        float v = (x[(size_t)n*CC + c] - m)*gg + bb;
        if (leaky) v = v > 0.f ? v : SLOPE*v;
        out[(size_t)n*CC + c] = v;
    }
}

// ---------------------------------------------------------------------------
// relay cross-attention; ykv HEAD-MAJOR f32 [16][NT][32] (k:0-7, v:8-15);
// rel [n][1280] (tr_k at +512, tr_v at +768, tr_q at +1024)
__global__ __launch_bounds__(64) void k_attn_tr(
    const float* __restrict__ rel, const float* __restrict__ ykv,
    const float* __restrict__ relay, float* __restrict__ out)
{
    int h = blockIdx.x, n = blockIdx.y, tid = threadIdx.x;
    __shared__ float sc[LL1];
    __shared__ float red[64][33];
    float q0[32];
    const float* qp = rel + (size_t)n*1280 + 1024 + h*32;
    #pragma unroll
    for (int j = 0; j < 8; j++) {
        float4 v = *(const float4*)&qp[j*4];
        q0[j*4] = v.x; q0[j*4+1] = v.y; q0[j*4+2] = v.z; q0[j*4+3] = v.w;
    }
    for (int l = tid; l < LL1; l += 64) {
        const float* kp = (l == 0) ? (rel + (size_t)n*1280 + 512 + h*32)
                                   : (ykv + ((size_t)h*NT + n*TT + l-1)*32);
        float s = 0.f;
        #pragma unroll
        for (int j = 0; j < 8; j++) {
            float4 v = *(const float4*)&kp[j*4];
            s += q0[j*4]*v.x + q0[j*4+1]*v.y + q0[j*4+2]*v.z + q0[j*4+3]*v.w;
        }
        sc[l] = s * SCALE_F;
    }
    __syncthreads();
    float mx = -1e30f;
    for (int l = tid; l < LL1; l += 64) mx = fmaxf(mx, sc[l]);
    for (int off = 32; off; off >>= 1) mx = fmaxf(mx, __shfl_xor(mx, off));
    float sum = 0.f;
    for (int l = tid; l < LL1; l += 64) { float e = expf(sc[l]-mx); sc[l] = e; sum += e; }
    for (int off = 32; off; off >>= 1) sum += __shfl_xor(sum, off);
    __syncthreads();
    float av[32];
    #pragma unroll
    for (int d = 0; d < 32; d++) av[d] = 0.f;
    for (int l = tid; l < LL1; l += 64) {
        float e = sc[l];
        const float* vp = (l == 0) ? (rel + (size_t)n*1280 + 768 + h*32)
                                   : (ykv + ((size_t)(8+h)*NT + n*TT + l-1)*32);
        #pragma unroll
        for (int j = 0; j < 8; j++) {
            float4 v = *(const float4*)&vp[j*4];
            av[j*4] += e*v.x; av[j*4+1] += e*v.y; av[j*4+2] += e*v.z; av[j*4+3] += e*v.w;
        }
    }
    #pragma unroll
    for (int d = 0; d < 32; d++) red[tid][d] = av[d];
    __syncthreads();
    if (tid < 32) {
        float a = 0.f;
        for (int k = 0; k < 64; k++) a += red[k][tid];
        a /= sum;
        int idx = n*CC + h*32 + tid;
        out[idx] = relay[idx] + a;
    }
}

// ---------------------------------------------------------------------------
extern "C" void kernel_launch(void* const* d_in, const int* in_sizes, int n_in,
                              void* d_out, int out_size, void* d_ws, size_t ws_size,
                              hipStream_t stream)
{
    const float* data    = (const float*)d_in[0];
    const float* ln_g    = (const float*)d_in[1];
    const float* ln_b    = (const float*)d_in[2];
    const float* tj_wq   = (const float*)d_in[3];
    const float* tj_bq   = (const float*)d_in[4];
    const float* tj_wk   = (const float*)d_in[5];
    const float* tj_bk   = (const float*)d_in[6];
    const float* tj_wv   = (const float*)d_in[7];
    const float* tj_bv   = (const float*)d_in[8];
    const float* tj_bn_g = (const float*)d_in[9];
    const float* tj_bn_b = (const float*)d_in[10];
    const float* tj_w1   = (const float*)d_in[11];
    const float* tj_b1   = (const float*)d_in[12];
    const float* tj_w2   = (const float*)d_in[13];
    const float* tj_b2   = (const float*)d_in[14];
    const float* tj_fbn_g= (const float*)d_in[15];
    const float* tj_fbn_b= (const float*)d_in[16];
    const float* tr_wq   = (const float*)d_in[17];
    const float* tr_bq   = (const float*)d_in[18];
    const float* tr_wk   = (const float*)d_in[19];
    const float* tr_bk   = (const float*)d_in[20];
    const float* tr_wv   = (const float*)d_in[21];
    const float* tr_bv   = (const float*)d_in[22];
    const float* tr_bn_g = (const float*)d_in[23];
    const float* tr_bn_b = (const float*)d_in[24];
    const float* tr_w1   = (const float*)d_in[25];
    const float* tr_b1   = (const float*)d_in[26];
    const float* tr_w2   = (const float*)d_in[27];
    const float* tr_b2   = (const float*)d_in[28];
    const float* tr_fbn_g= (const float*)d_in[29];
    const float* tr_fbn_b= (const float*)d_in[30];

    const size_t SZ = (size_t)NT*CC;     // 6,553,600
    const size_t SZ_NC = (size_t)NN*CC;

    float* ws = (float*)d_ws;
    size_t off = 0;
    auto alloc = [&](size_t nf) { float* p = ws + off; off += nf; return p; };
    float*    nodesf  = alloc(SZ);          // TM f32: xln (layer0 LN in-place)
    float*    sbuf    = alloc(SZ);          // TM f32: s1 / s1b (FFN2 in-place)
    float*    P1      = alloc(SZ*5/2);      // qkv(1.5)+ekv(1.0) bf16 | h(2.0) bf16 | ykv(2.0) f32
    ushort_t* xs_bf   = (ushort_t*)alloc(SZ/2);  // xln_bf / s2_bf (TM)
    ushort_t* embs_bf = (ushort_t*)alloc(SZ/2);  // TM, persists
    ushort_t* nb_bf   = (ushort_t*)alloc(SZ/2);  // nodes bf16 (pre-LN), for ykv
    float* accs   = alloc(8*512);           // raw BN sums, 2 per layer
    float* relayA = alloc(SZ_NC);
    float* relayB = alloc(SZ_NC);
    float* rel    = alloc((size_t)NN*1280); // fused relay projections
    float* ret0   = alloc(SZ_NC);
    float* rret   = alloc(SZ_NC);
    float* ro     = alloc(SZ_NC);
    float* rh     = alloc((size_t)NN*DFFF);
    ushort_t* wqkv_bf  = (ushort_t*)alloc((size_t)ITER*768*CC/2);
    ushort_t* wkvtr_bf = (ushort_t*)alloc((size_t)ITER*512*CC/2);
    ushort_t* w1_bf    = (ushort_t*)alloc((size_t)ITER*DFFF*CC/2);
    ushort_t* w2_bf    = (ushort_t*)alloc((size_t)ITER*DFFF*CC/2);
    float* wrel  = alloc((size_t)ITER*1280*CC);
    float* brel  = alloc((size_t)ITER*1280);
    float* bqkv  = alloc((size_t)ITER*768);
    float* bkvtr = alloc((size_t)ITER*512);
    (void)ws_size; (void)in_sizes; (void)n_in; (void)out_size;

    ushort_t* qkv_tm = (ushort_t*)P1;           // HM [24][NT][32] bf16
    ushort_t* ekv_tm = qkv_tm + 3*SZ;           // HM [16][NT][32] bf16
    ushort_t* h_us   = (ushort_t*)P1;           // TM [nt][1024] bf16 (after attn)
    float*    ykv_f  = P1;                      // HM [16][NT][32] f32 (after FFN2)

    const int TFF = ITER*DFFF*CC;
    // R17: fused prologue — 4 launches instead of 21
    k_prep_small<<<56, 256, 0, stream>>>(
        tj_bq, tj_bk, tj_bv, tr_bq, tr_bk, tr_bv, bqkv, bkvtr, brel, accs);
    k_prep_w<<<10240, 256, 0, stream>>>(
        tj_wq, tj_wk, tj_wv, tr_wk, tr_wv, tr_wq, wqkv_bf, wkvtr_bf, wrel);
    k_cast2<<<(TFF+255)/256, 256, 0, stream>>>(tj_w1, w1_bf, TFF, TFF, TFF);
    k_cast2<<<(TFF+255)/256, 256, 0, stream>>>(tj_w2, w2_bf, TFF, TFF, TFF);

    k_embed<<<dim3(8, NN), 128, 0, stream>>>(data, nodesf, embs_bf, relayA);
    k_layernorm<<<NT/4, 256, 0, stream>>>(nodesf, xs_bf, ln_g, ln_b);

    float* relay = relayA;
    float* relay_next = relayB;
    dim3 sb16(16, 16);

    for (int i = 0; i < ITER; i++) {
        const size_t woff = (size_t)i*DFFF*CC;
        float* accA = accs + i*1024;
        float* accB = accs + i*1024 + 512;

        // fused relay projections: rel[n][1280] (layer3 needs only first 512)
        k_sgemm<<<dim3((i == ITER-1) ? 32 : 80, 13), sb16, 0, stream>>>(
            wrel + (size_t)i*1280*CC, relay, brel + i*1280, nullptr, rel, CC, 1280, 0);

        // merged qkv (6 n-tiles, A=xs_bf) + ekv (4 n-tiles, A=embs_bf),
        // head-major outputs
        k_gemm_mfma<256,0><<<200*10, 512, 0, stream>>>(
            xs_bf, wqkv_bf + (size_t)i*768*CC, bqkv + i*768,
            nullptr, nullptr, nullptr, nullptr,
            nullptr, qkv_tm, 768, 6, FL_BF16 | FL_HM,
            embs_bf, wqkv_bf + (size_t)i*768*CC + 65536, bqkv + i*768 + 256,
            ekv_tm, 512, 4, nullptr);

        // attn (zero-LDS, head-major streams)
        k_attn_tj<<<dim3(NHH, NN), 128, 0, stream>>>(qkv_tm, ekv_tm, rel, nodesf, sbuf);

        k_bnstats_tm<<<NN, 256, 0, stream>>>(sbuf, accA);
        k_bn_apply_raw<<<SZ/1024, 256, 0, stream>>>(
            sbuf, accA, tj_bn_g + i*CC, tj_bn_b + i*CC, xs_bf);

        // FFN1: h = relu(W1*s2+b1), [nt][1024] bf16 (TM)
        k_gemm_mfma<256,0><<<200*8, 512, 0, stream>>>(
            xs_bf, w1_bf + woff, tj_b1 + i*DFFF, nullptr, nullptr, nullptr, nullptr,
            nullptr, h_us, DFFF, 8, FL_RELU | FL_BF16,
            nullptr, nullptr, nullptr, nullptr, 0, 0, nullptr);
        // FFN2: sbuf = W2*h + b2 + BN1(sbuf), fused BN stats -> accB
        k_gemm_mfma<1024,1><<<200*2, 512, 0, stream>>>(
            h_us, w2_bf + woff, tj_b2 + i*CC, sbuf, accA, tj_bn_g + i*CC, tj_bn_b + i*CC,
            sbuf, nullptr, CC, 2, FL_RESBN,
            nullptr, nullptr, nullptr, nullptr, 0, 0, accB);

        if (i == ITER-1) {
            k_bn_out_t<<<dim3(NT/64, CC/64), 256, 0, stream>>>(
                sbuf, accB, tj_fbn_g + i*CC, tj_fbn_b + i*CC, (float*)d_out);
            break;   // last relay update is dead code
        }
        // fused BN2+leaky+LN(i+1): nodes_bf + xln f32 + xln bf16
        k_bn_ln<<<NT/4, 256, 0, stream>>>(
            sbuf, accB, tj_fbn_g + i*CC, tj_fbn_b + i*CC,
            ln_g + (i+1)*CC, ln_b + (i+1)*CC, nodesf, xs_bf, nb_bf);

        // relay path: ykv = W_kv^tr * nodes, head-major f32
        k_gemm_mfma<256,0><<<200*4, 512, 0, stream>>>(
            nb_bf, wkvtr_bf + (size_t)i*512*CC, bkvtr + i*512,
            nullptr, nullptr, nullptr, nullptr,
            ykv_f, nullptr, 512, 4, FL_HM,
            nullptr, nullptr, nullptr, nullptr, 0, 0, nullptr);

        k_attn_tr<<<dim3(NHH, NN), 64, 0, stream>>>(rel, ykv_f, relay, ret0);
        k_bn_relay<<<CC, 64, 0, stream>>>(ret0, rret, tr_bn_g + i*CC, tr_bn_b + i*CC, 0);

        k_sgemm<<<dim3(DFFF/16, (NN+15)/16), sb16, 0, stream>>>(
            tr_w1 + woff, rret, tr_b1 + i*DFFF, nullptr, rh, CC, DFFF, 1);
        k_sgemm<<<dim3(16, (NN+15)/16), sb16, 0, stream>>>(
            tr_w2 + woff, rh, tr_b2 + i*CC, rret, ro, DFFF, CC, 0);
        k_bn_relay<<<CC, 64, 0, stream>>>(ro, relay_next, tr_fbn_g + i*CC, tr_fbn_b + i*CC, 1);

        float* tmp = relay; relay = relay_next; relay_next = tmp;
    }
}